// Round 8
// baseline (380.470 us; speedup 1.0000x reference)
//
#include <hip/hip_runtime.h>
#include <hip/hip_bf16.h>
#include <math.h>

static constexpr int Bn = 8, Cn = 32, Hn = 256, Wn = 256;
static constexpr int HP = 258;                      // padded pitch (1-px zero border)
static constexpr size_t PLANE = (size_t)Hn * Wn;    // 65536

typedef __attribute__((ext_vector_type(8))) short bf16x8;   // MFMA A/B frag (4 VGPRs)
typedef __attribute__((ext_vector_type(4))) float f32x4;    // MFMA C/D frag
typedef __attribute__((ext_vector_type(4))) short s16x4;    // 4 bf16 = 8 B store
typedef __attribute__((ext_vector_type(4))) int   i32x4;    // 16 B copy

__device__ inline short bf16bits(float v) {
    union { __hip_bfloat16 h; short s; } u; u.h = __float2bfloat16(v);
    return u.s;
}
__device__ inline float bits2f(short s) {
    union { unsigned int u; float f; } u; u.u = ((unsigned int)(unsigned short)s) << 16;
    return u.f;
}
__device__ inline unsigned int pack2(float lo, float hi) {
    return (unsigned int)(unsigned short)bf16bits(lo)
         | ((unsigned int)(unsigned short)bf16bits(hi) << 16);
}
// async global->LDS, 16 B per lane; LDS dst wave-uniform (HW adds lane*16)
__device__ inline void async16(const short* g, short* l) {
    __builtin_amdgcn_global_load_lds(
        (const __attribute__((address_space(1))) unsigned int*)g,
        (__attribute__((address_space(3))) unsigned int*)l, 16, 0, 0);
}

// ---------------------------------------------------------------------------
// Pack conv weights fp32 OIHW [32][CIN][3][3] -> bf16 wp[cb][s][mt][m][gpos][j]
// in MFMA A-frag order with XOR bank swizzle: position gpos holds logical
// g = gpos ^ ((m>>2)&3)  => conv's wf read (lane m,g at gpos=g^((m>>2)&3))
// hits all 8 bank-groups exactly 2x (2-way = free).
// ---------------------------------------------------------------------------
template <int CIN>
__global__ __launch_bounds__(256) void pack_w(const float* __restrict__ w,
                                              __hip_bfloat16* __restrict__ wp)
{
    int idx = blockIdx.x * 256 + threadIdx.x;        // total 9*CB*1024
    int j = idx & 7, gpos = (idx >> 3) & 3, m = (idx >> 5) & 15, mt = (idx >> 9) & 1;
    int rest = idx >> 10;
    int s = rest % 9, cb = rest / 9;
    int g = gpos ^ ((m >> 2) & 3);                   // logical k-group
    int co = mt * 16 + m;
    int ci = cb * 32 + g * 8 + j;
    float v = w[((size_t)(co * CIN + ci) * 3 + s / 3) * 3 + (s % 3)];
    wp[idx] = __float2bfloat16(v);
}

// ---------------------------------------------------------------------------
// Zero the 1-px border of a padded NHWC [b][258][258][C] bf16 buffer.
// ---------------------------------------------------------------------------
template <int C>
__global__ __launch_bounds__(256) void zero_border(short* __restrict__ p)
{
    constexpr int CH8 = C / 8;
    int idx = blockIdx.x * 256 + threadIdx.x;
    if (idx >= 8 * 1028 * CH8) return;
    int c8 = idx % CH8;
    int rest = idx / CH8;
    int pe = rest % 1028, b = rest / 1028;
    int y, x;
    if (pe < 258)      { y = 0;   x = pe; }
    else if (pe < 516) { y = 257; x = pe - 258; }
    else if (pe < 772) { y = pe - 516 + 1; x = 0; }
    else               { y = pe - 772 + 1; x = 257; }
    *(i32x4*)(p + ((size_t)(b * HP + y) * HP + x) * C + c8 * 8) = i32x4{};
}

// ---------------------------------------------------------------------------
// x (fp32 NCHW, C=32) -> bf16 padded NHWC [b][258][258][32] interior.
// ---------------------------------------------------------------------------
__global__ __launch_bounds__(256) void x_to_nhwc(const float* __restrict__ in,
                                                 __hip_bfloat16* __restrict__ out)
{
    __shared__ unsigned int shU[32 * 17];
    unsigned short* sh16 = (unsigned short*)shU;
    int tid = threadIdx.x;
    int px0 = blockIdx.x * 32;
    int b = blockIdx.y;
    const float2* in2 = (const float2*)(in + ((size_t)b * 32) * PLANE + px0);
    for (int i = tid; i < 512; i += 256) {
        int ch = i >> 4, pxp = i & 15;
        float2 v = in2[(size_t)ch * (PLANE / 2) + pxp];
        unsigned int lo = (unsigned short)bf16bits(v.x);
        unsigned int hi = (unsigned short)bf16bits(v.y);
        shU[ch * 17 + pxp] = lo | (hi << 16);
    }
    __syncthreads();
    int yy = px0 >> 8, xx0 = px0 & 255;
    unsigned int* out32 = (unsigned int*)out
        + ((size_t)(b * HP + yy + 1) * HP + xx0 + 1) * 16;
    for (int i = tid; i < 512; i += 256) {
        int px = i >> 4, chp = i & 15;
        unsigned int v = (unsigned int)sh16[(2 * chp) * 34 + px]
                       | ((unsigned int)sh16[(2 * chp + 1) * 34 + px] << 16);
        out32[(size_t)px * 16 + chp] = v;
    }
}

// ---------------------------------------------------------------------------
// MFMA implicit-GEMM 3x3 SAME conv. Input padded NHWC bf16 [b][258][258][CIN].
// M = co (weights), N = x (pixels). Block (4 waves): 8 y x 32 x x 32 co.
// Slab chunks XOR-swizzled: (yy,xx,g) stored at gpos = g ^ ((xx>>2)&3)
// -> all K-loop ds_reads are 2-way per bank group (free).
// Row-reuse: per dx, 4 B-row frags loaded once into regs, reused across dy
// (B-reads 36 -> 24 per cb per wave).
// Async double-buffered staging of slab + weight slice (80384 B, 2 blk/CU);
// compute phase has zero VMEM.
// FUSE: conv1x1(wo)+sigmoid epilogue, writes fp32 mask directly.
// ---------------------------------------------------------------------------
template <int CIN, bool RELU, bool FUSE>
__global__ __launch_bounds__(256, 2) void conv_mfma(const __hip_bfloat16* __restrict__ in,
        const __hip_bfloat16* __restrict__ wp, __hip_bfloat16* __restrict__ outA,
        const float* __restrict__ wo, float* __restrict__ outF)
{
    constexpr int CB = CIN / 32;
    constexpr int SLAB = 10880;              // 10*34*32 shorts
    constexpr int WSL  = 9216;               // 9*1024 shorts
    constexpr int BUF  = SLAB + WSL;         // 20096 shorts / buffer
    __shared__ short sIn[2 * BUF];           // 80384 B -> 2 blocks/CU
    int tid = threadIdx.x;
    int lane = tid & 63, wave = tid >> 6;
    int m = lane & 15, g = lane >> 4;
    int x0 = blockIdx.x * 32, y0 = blockIdx.y * 8, b = blockIdx.z;

    const short* inS = (const short*)in;
    const short* wpS = (const short*)wp;
    f32x4 acc[2][2][2] = {};                 // [wy][mt(co)][nt(x)]

    auto stage = [&](int buf, int cb) {
        short* dst = sIn + buf * BUF;
        // slab: 1360 x 16 B; position gpos holds logical g = gpos ^ sw(xx)
        #pragma unroll
        for (int r = 0; r < 6; ++r) {
            int i = r * 256 + tid;
            if (r < 5 || i < 1360) {
                int gpos = i & 3, q = i >> 2;            // q = yy*34+xx
                int xx = q % 34, yy = q / 34;
                int gl = gpos ^ ((xx >> 2) & 3);
                const short* gp = inS
                    + ((size_t)(b * HP + y0 + yy) * HP + x0 + xx) * CIN
                    + cb * 32 + gl * 8;
                async16(gp, dst + (r * 256 + wave * 64) * 8);
            }
        }
        // weight slice: 1152 x 16 B straight copy (pre-swizzled by pack_w)
        #pragma unroll
        for (int r = 0; r < 5; ++r) {
            int i = r * 256 + tid;
            if (r < 4 || i < 1152) {
                const short* gp = wpS + (size_t)cb * WSL + i * 8;
                async16(gp, dst + SLAB + (r * 256 + wave * 64) * 8);
            }
        }
    };

    int wfoff = (m * 4 + (g ^ ((m >> 2) & 3))) * 8;      // swizzled wf position

    stage(0, 0);
    for (int cb = 0; cb < CB; ++cb) {
        __syncthreads();                     // buf(cb) ready (vmcnt drain)
        if (cb + 1 < CB) stage((cb + 1) & 1, cb + 1);    // overlaps compute(cb)
        const short* sb = sIn + (cb & 1) * BUF;
        const short* sw = sb + SLAB;

        #pragma unroll
        for (int dxr = 0; dxr < 3; ++dxr) {
            int xx = m + dxr;                             // slab col (nt=0)
            const short* colp = sb + xx * 32 + (g ^ ((xx >> 2) & 3)) * 8;
            bf16x8 Bf[4][2];
            #pragma unroll
            for (int rr = 0; rr < 4; ++rr) {              // slab rows 2w..2w+3
                const short* rp = colp + (wave * 2 + rr) * (34 * 32);
                Bf[rr][0] = *(const bf16x8*)rp;
                Bf[rr][1] = *(const bf16x8*)(rp + 16 * 32);   // +16 x (same swz)
            }
            #pragma unroll
            for (int dyi = 0; dyi < 3; ++dyi) {
                int s = dyi * 3 + dxr;
                bf16x8 wf0 = *(const bf16x8*)(sw + s * 1024 + wfoff);
                bf16x8 wf1 = *(const bf16x8*)(sw + s * 1024 + 512 + wfoff);
                #pragma unroll
                for (int wy = 0; wy < 2; ++wy) {
                    int rr = wy + dyi;
                    acc[wy][0][0] = __builtin_amdgcn_mfma_f32_16x16x32_bf16(wf0, Bf[rr][0], acc[wy][0][0], 0, 0, 0);
                    acc[wy][1][0] = __builtin_amdgcn_mfma_f32_16x16x32_bf16(wf1, Bf[rr][0], acc[wy][1][0], 0, 0, 0);
                    acc[wy][0][1] = __builtin_amdgcn_mfma_f32_16x16x32_bf16(wf0, Bf[rr][1], acc[wy][0][1], 0, 0, 0);
                    acc[wy][1][1] = __builtin_amdgcn_mfma_f32_16x16x32_bf16(wf1, Bf[rr][1], acc[wy][1][1], 0, 0, 0);
                }
            }
        }
    }

    // D layout: row (= co-in-tile) = g*4 + reg, col (= x-offset) = lane&15.
    if (FUSE) {
        float wv[2][4];
        #pragma unroll
        for (int mt = 0; mt < 2; ++mt)
            #pragma unroll
            for (int r = 0; r < 4; ++r) wv[mt][r] = wo[mt * 16 + g * 4 + r];
        #pragma unroll
        for (int wy = 0; wy < 2; ++wy) {
            int y = y0 + wave * 2 + wy;
            #pragma unroll
            for (int nt = 0; nt < 2; ++nt) {
                float s = 0.f;
                #pragma unroll
                for (int mt = 0; mt < 2; ++mt)
                    #pragma unroll
                    for (int r = 0; r < 4; ++r)
                        s = fmaf(fmaxf(acc[wy][mt][nt][r], 0.f), wv[mt][r], s);
                s += __shfl_xor(s, 16);
                s += __shfl_xor(s, 32);
                if (g == 0)
                    outF[(size_t)(b * 256 + y) * 256 + x0 + nt * 16 + m]
                        = 1.f / (1.f + expf(-s));
            }
        }
    } else {
        short* outS = (short*)outA;
        #pragma unroll
        for (int wy = 0; wy < 2; ++wy) {
            int y = y0 + wave * 2 + wy;
            #pragma unroll
            for (int nt = 0; nt < 2; ++nt) {
                int x = x0 + nt * 16 + m;
                size_t base = ((size_t)((b * 256 + y) * 256 + x)) * 32;
                #pragma unroll
                for (int mt = 0; mt < 2; ++mt) {
                    int co = mt * 16 + g * 4;
                    s16x4 ov;
                    #pragma unroll
                    for (int r = 0; r < 4; ++r) {
                        float v = acc[wy][mt][nt][r];
                        if (RELU) v = fmaxf(v, 0.f);
                        ov[r] = bf16bits(v);
                    }
                    *(s16x4*)(outS + base + co) = ov;
                }
            }
        }
    }
}

// ---------------------------------------------------------------------------
// Segmented IRNN (|w|<=0.2: 16-step warm-up => exact to ~1e-11), both
// directions per kernel, 2 channels per thread (4 B units), direct global
// reads (A = 32 MiB, L2/L3-hot). 32-len segments, grid 1024 blocks.
// VERT: thread (c16, xo:16); wave reads/writes dense 256 B segments.
// ---------------------------------------------------------------------------
__global__ __launch_bounds__(256) void irnn_vert(const __hip_bfloat16* __restrict__ A,
        const float* __restrict__ w4, const float* __restrict__ b4,
        __hip_bfloat16* __restrict__ I)
{
    int tid = threadIdx.x;
    int c16 = tid & 15, xo = tid >> 4;
    int x = blockIdx.x * 16 + xo;
    int y1 = blockIdx.y * 32;
    int b = blockIdx.z;
    const unsigned int* ap = (const unsigned int*)A + ((size_t)b * PLANE + x) * 16 + c16;
    unsigned int* ob = (unsigned int*)I + ((size_t)(b * HP + 1) * HP + 1 + x) * 64 + c16;
    const size_t as = 256 * 16, os = (size_t)HP * 64;

    // down (dir 2): increasing y
    {
        float w0 = w4[64 + 2 * c16], w1 = w4[64 + 2 * c16 + 1];
        float B0 = b4[64 + 2 * c16], B1 = b4[64 + 2 * c16 + 1];
        unsigned int* o = ob + 2 * 16;
        int ys = y1 - 16; if (ys < 0) ys = 0;
        unsigned int v = ap[(size_t)ys * as];
        float h0 = bits2f((short)v), h1 = bits2f((short)(v >> 16));
        if (ys == y1) o[(size_t)ys * os] = pack2(h0, h1);
        #pragma unroll 8
        for (int y = ys + 1; y < y1 + 32; ++y) {
            v = ap[(size_t)y * as];
            h0 = fmaxf(fmaf(w0, h0, B0 + bits2f((short)v)), 0.f);
            h1 = fmaxf(fmaf(w1, h1, B1 + bits2f((short)(v >> 16))), 0.f);
            if (y >= y1) o[(size_t)y * os] = pack2(h0, h1);
        }
    }
    // up (dir 0): decreasing y
    {
        float w0 = w4[2 * c16], w1 = w4[2 * c16 + 1];
        float B0 = b4[2 * c16], B1 = b4[2 * c16 + 1];
        unsigned int* o = ob;
        int ye = y1 + 47; if (ye > 255) ye = 255;
        unsigned int v = ap[(size_t)ye * as];
        float h0 = bits2f((short)v), h1 = bits2f((short)(v >> 16));
        if (ye == y1 + 31) o[(size_t)ye * os] = pack2(h0, h1);
        #pragma unroll 8
        for (int y = ye - 1; y >= y1; --y) {
            v = ap[(size_t)y * as];
            h0 = fmaxf(fmaf(w0, h0, B0 + bits2f((short)v)), 0.f);
            h1 = fmaxf(fmaf(w1, h1, B1 + bits2f((short)(v >> 16))), 0.f);
            if (y <= y1 + 31) o[(size_t)y * os] = pack2(h0, h1);
        }
    }
}

// HORIZ: thread (c16, yo:16); scan over x.
__global__ __launch_bounds__(256) void irnn_horiz(const __hip_bfloat16* __restrict__ A,
        const float* __restrict__ w4, const float* __restrict__ b4,
        __hip_bfloat16* __restrict__ I)
{
    int tid = threadIdx.x;
    int c16 = tid & 15, yo = tid >> 4;
    int y = blockIdx.x * 16 + yo;
    int x1 = blockIdx.y * 32;
    int b = blockIdx.z;
    const unsigned int* ap = (const unsigned int*)A + ((size_t)b * PLANE + (size_t)y * 256) * 16 + c16;
    unsigned int* ob = (unsigned int*)I + ((size_t)(b * HP + 1 + y) * HP + 1) * 64 + c16;

    // right (dir 1): increasing x
    {
        float w0 = w4[32 + 2 * c16], w1 = w4[32 + 2 * c16 + 1];
        float B0 = b4[32 + 2 * c16], B1 = b4[32 + 2 * c16 + 1];
        unsigned int* o = ob + 16;
        int xs = x1 - 16; if (xs < 0) xs = 0;
        unsigned int v = ap[(size_t)xs * 16];
        float h0 = bits2f((short)v), h1 = bits2f((short)(v >> 16));
        if (xs == x1) o[(size_t)xs * 64] = pack2(h0, h1);
        #pragma unroll 8
        for (int x = xs + 1; x < x1 + 32; ++x) {
            v = ap[(size_t)x * 16];
            h0 = fmaxf(fmaf(w0, h0, B0 + bits2f((short)v)), 0.f);
            h1 = fmaxf(fmaf(w1, h1, B1 + bits2f((short)(v >> 16))), 0.f);
            if (x >= x1) o[(size_t)x * 64] = pack2(h0, h1);
        }
    }
    // left (dir 3): decreasing x
    {
        float w0 = w4[96 + 2 * c16], w1 = w4[96 + 2 * c16 + 1];
        float B0 = b4[96 + 2 * c16], B1 = b4[96 + 2 * c16 + 1];
        unsigned int* o = ob + 48;
        int xe = x1 + 47; if (xe > 255) xe = 255;
        unsigned int v = ap[(size_t)xe * 16];
        float h0 = bits2f((short)v), h1 = bits2f((short)(v >> 16));
        if (xe == x1 + 31) o[(size_t)xe * 64] = pack2(h0, h1);
        #pragma unroll 8
        for (int x = xe - 1; x >= x1; --x) {
            v = ap[(size_t)x * 16];
            h0 = fmaxf(fmaf(w0, h0, B0 + bits2f((short)v)), 0.f);
            h1 = fmaxf(fmaf(w1, h1, B1 + bits2f((short)(v >> 16))), 0.f);
            if (x <= x1 + 31) o[(size_t)x * 64] = pack2(h0, h1);
        }
    }
}

// ---------------------------------------------------------------------------
extern "C" void kernel_launch(void* const* d_in, const int* in_sizes, int n_in,
                              void* d_out, int out_size, void* d_ws, size_t ws_size,
                              hipStream_t stream)
{
    const float* x    = (const float*)d_in[0];
    const float* w_in = (const float*)d_in[1];
    const float* w2   = (const float*)d_in[2];
    const float* w3   = (const float*)d_in[3];
    const float* wo   = (const float*)d_in[4];
    const float* i1w  = (const float*)d_in[5];
    const float* i1b  = (const float*)d_in[6];
    const float* i2w  = (const float*)d_in[7];
    const float* i2b  = (const float*)d_in[8];
    float* out = (float*)d_out;

    char* ws = (char*)d_ws;
    // Ipad: padded NHWC bf16 [8][258][258][128] = 130 MiB @ 0
    //   (xTpad [8][258][258][32] aliases its head; dead before irnn1)
    __hip_bfloat16* Ipad  = (__hip_bfloat16*)ws;
    __hip_bfloat16* xTpad = (__hip_bfloat16*)ws;
    // A: NHWC bf16 [8][256][256][32] = 32 MiB @ 137 MB
    __hip_bfloat16* A = (__hip_bfloat16*)(ws + ((size_t)137 << 20));
    // packed weights @ 170 MiB
    __hip_bfloat16* wp1 = (__hip_bfloat16*)(ws + ((size_t)170 << 20));
    __hip_bfloat16* wp2 = (__hip_bfloat16*)(ws + ((size_t)170 << 20) + ((size_t)1 << 19));
    __hip_bfloat16* wp3 = (__hip_bfloat16*)(ws + ((size_t)170 << 20) + ((size_t)2 << 19));

    dim3 convGrid(8, 32, 8);      // 32-x strips, 8-y chunks, 8 b = 2048 blocks
    dim3 irnnGrid(16, 8, 8);      // 16-line chunks, 8 segs(32), 8 b = 1024 blocks

    pack_w<32> <<<36,  256, 0, stream>>>(w_in, wp1);
    pack_w<128><<<144, 256, 0, stream>>>(w2, wp2);
    pack_w<128><<<144, 256, 0, stream>>>(w3, wp3);

    zero_border<32><<<129, 256, 0, stream>>>((short*)xTpad);
    x_to_nhwc<<<dim3(2048, 8), 256, 0, stream>>>(x, xTpad);
    conv_mfma<32, false, false><<<convGrid, 256, 0, stream>>>(xTpad, wp1, A, nullptr, nullptr);

    zero_border<128><<<514, 256, 0, stream>>>((short*)Ipad);
    irnn_vert <<<irnnGrid, 256, 0, stream>>>(A, i1w, i1b, Ipad);
    irnn_horiz<<<irnnGrid, 256, 0, stream>>>(A, i1w, i1b, Ipad);
    conv_mfma<128, false, false><<<convGrid, 256, 0, stream>>>(Ipad, wp2, A, nullptr, nullptr);

    irnn_vert <<<irnnGrid, 256, 0, stream>>>(A, i2w, i2b, Ipad);
    irnn_horiz<<<irnnGrid, 256, 0, stream>>>(A, i2w, i2b, Ipad);
    // conv3 + relu + conv1x1 + sigmoid fused; writes fp32 mask directly
    conv_mfma<128, true, true><<<convGrid, 256, 0, stream>>>(Ipad, wp3, nullptr, wo, out);
}

// Round 9
// 309.869 us; speedup vs baseline: 1.2278x; 1.2278x over previous
//
#include <hip/hip_runtime.h>
#include <hip/hip_bf16.h>
#include <math.h>

static constexpr int Bn = 8, Cn = 32, Hn = 256, Wn = 256;
static constexpr int HP = 258;                      // padded pitch (1-px zero border)
static constexpr size_t PLANE = (size_t)Hn * Wn;    // 65536
static constexpr size_t PB = (size_t)HP * HP;       // padded pixels per image

typedef __attribute__((ext_vector_type(8))) short bf16x8;   // MFMA A/B frag (4 VGPRs)
typedef __attribute__((ext_vector_type(4))) float f32x4;    // MFMA C/D frag
typedef __attribute__((ext_vector_type(4))) short s16x4;    // 4 bf16 = 8 B store
typedef __attribute__((ext_vector_type(4))) int   i32x4;    // 16 B copy

__device__ inline short bf16bits(float v) {
    union { __hip_bfloat16 h; short s; } u; u.h = __float2bfloat16(v);
    return u.s;
}
__device__ inline float bits2f(short s) {
    union { unsigned int u; float f; } u; u.u = ((unsigned int)(unsigned short)s) << 16;
    return u.f;
}
// async global->LDS, 16 B per lane; LDS dst wave-uniform (HW adds lane*16)
__device__ inline void async16(const short* g, short* l) {
    __builtin_amdgcn_global_load_lds(
        (const __attribute__((address_space(1))) unsigned int*)g,
        (__attribute__((address_space(3))) unsigned int*)l, 16, 0, 0);
}

// ---------------------------------------------------------------------------
// Pack conv weights fp32 OIHW [32][CIN][3][3] -> bf16 wp[cb][s][mt][m][gpos][j]
// (A-frag order, M-side = co), XOR bank swizzle gpos = g ^ ((m>>2)&3).
// cb = input-channel block of 32 = dir plane (concat order up,right,down,left).
// ---------------------------------------------------------------------------
template <int CIN>
__global__ __launch_bounds__(256) void pack_w(const float* __restrict__ w,
                                              __hip_bfloat16* __restrict__ wp)
{
    int idx = blockIdx.x * 256 + threadIdx.x;        // total 9*CB*1024
    int j = idx & 7, gpos = (idx >> 3) & 3, m = (idx >> 5) & 15, mt = (idx >> 9) & 1;
    int rest = idx >> 10;
    int s = rest % 9, cb = rest / 9;
    int g = gpos ^ ((m >> 2) & 3);                   // logical k-group
    int co = mt * 16 + m;
    int ci = cb * 32 + g * 8 + j;
    float v = w[((size_t)(co * CIN + ci) * 3 + s / 3) * 3 + (s % 3)];
    wp[idx] = __float2bfloat16(v);
}

// ---------------------------------------------------------------------------
// Zero the 1-px border of NB padded [258][258][32] bf16 planes.
// ---------------------------------------------------------------------------
template <int NB>
__global__ __launch_bounds__(256) void zero_border(short* __restrict__ p)
{
    int idx = blockIdx.x * 256 + threadIdx.x;
    if (idx >= NB * 1028 * 4) return;
    int c8 = idx & 3;
    int rest = idx >> 2;
    int pe = rest % 1028, bb = rest / 1028;
    int y, x;
    if (pe < 258)      { y = 0;   x = pe; }
    else if (pe < 516) { y = 257; x = pe - 258; }
    else if (pe < 772) { y = pe - 516 + 1; x = 0; }
    else               { y = pe - 772 + 1; x = 257; }
    *(i32x4*)(p + ((size_t)bb * PB + (size_t)y * HP + x) * 32 + c8 * 8) = i32x4{};
}

// ---------------------------------------------------------------------------
// x (fp32 NCHW, C=32) -> bf16 padded [b][258][258][32] interior.
// ---------------------------------------------------------------------------
__global__ __launch_bounds__(256) void x_to_nhwc(const float* __restrict__ in,
                                                 __hip_bfloat16* __restrict__ out)
{
    __shared__ unsigned int shU[32 * 17];
    unsigned short* sh16 = (unsigned short*)shU;
    int tid = threadIdx.x;
    int px0 = blockIdx.x * 32;
    int b = blockIdx.y;
    const float2* in2 = (const float2*)(in + ((size_t)b * 32) * PLANE + px0);
    for (int i = tid; i < 512; i += 256) {
        int ch = i >> 4, pxp = i & 15;
        float2 v = in2[(size_t)ch * (PLANE / 2) + pxp];
        unsigned int lo = (unsigned short)bf16bits(v.x);
        unsigned int hi = (unsigned short)bf16bits(v.y);
        shU[ch * 17 + pxp] = lo | (hi << 16);
    }
    __syncthreads();
    int yy = px0 >> 8, xx0 = px0 & 255;
    unsigned int* out32 = (unsigned int*)out
        + ((size_t)b * PB + (size_t)(yy + 1) * HP + xx0 + 1) * 16;
    for (int i = tid; i < 512; i += 256) {
        int px = i >> 4, chp = i & 15;
        unsigned int v = (unsigned int)sh16[(2 * chp) * 34 + px]
                       | ((unsigned int)sh16[(2 * chp + 1) * 34 + px] << 16);
        out32[(size_t)px * 16 + chp] = v;
    }
}

// ---------------------------------------------------------------------------
// MFMA implicit-GEMM 3x3 SAME conv. Input: CB planar padded [cb][b][258][258][32]
// bf16 planes (cb = ci-block / dir). Output: NHWC bf16 [b][256][256][32] or
// (FUSE) fp32 sigmoid mask. Block (4 waves): 8 y x 32 x x 32 co.
// Async double-buffered global_load_lds staging (slab 10x34x32 + 9 KB weights,
// 80384 B LDS, 2 blocks/CU); compute phase: ds_read + MFMA only.
// Row-reuse: per dx, 4 B-row frags loaded once, reused across dy.
// ---------------------------------------------------------------------------
template <int CIN, bool RELU, bool FUSE>
__global__ __launch_bounds__(256, 2) void conv_mfma(const __hip_bfloat16* __restrict__ in,
        const __hip_bfloat16* __restrict__ wp, __hip_bfloat16* __restrict__ outA,
        const float* __restrict__ wo, float* __restrict__ outF)
{
    constexpr int CB = CIN / 32;
    constexpr int SLAB = 10880;              // 10*34*32 shorts
    constexpr int WSL  = 9216;               // 9*1024 shorts
    constexpr int BUF  = SLAB + WSL;         // 20096 shorts / buffer
    __shared__ short sIn[2 * BUF];           // 80384 B -> 2 blocks/CU
    int tid = threadIdx.x;
    int lane = tid & 63, wave = tid >> 6;
    int m = lane & 15, g = lane >> 4;
    int x0 = blockIdx.x * 32, y0 = blockIdx.y * 8, b = blockIdx.z;

    const short* inS = (const short*)in;
    const short* wpS = (const short*)wp;
    f32x4 acc[2][2][2] = {};                 // [wy][mt(co)][nt(x)]

    auto stage = [&](int buf, int cb) {
        short* dst = sIn + buf * BUF;
        // slab: 1360 x 16 B from plane (cb,b); gpos holds g = gpos ^ sw(xx)
        #pragma unroll
        for (int r = 0; r < 6; ++r) {
            int i = r * 256 + tid;
            if (r < 5 || i < 1360) {
                int gpos = i & 3, q = i >> 2;            // q = yy*34+xx
                int xx = q % 34, yy = q / 34;
                int gl = gpos ^ ((xx >> 2) & 3);
                const short* gp = inS
                    + ((size_t)(cb * 8 + b) * PB + (size_t)(y0 + yy) * HP + x0 + xx) * 32
                    + gl * 8;
                async16(gp, dst + (r * 256 + wave * 64) * 8);
            }
        }
        // weight slice: 1152 x 16 B straight copy (pre-swizzled by pack_w)
        #pragma unroll
        for (int r = 0; r < 5; ++r) {
            int i = r * 256 + tid;
            if (r < 4 || i < 1152) {
                const short* gp = wpS + (size_t)cb * WSL + i * 8;
                async16(gp, dst + SLAB + (r * 256 + wave * 64) * 8);
            }
        }
    };

    int wfoff = (m * 4 + (g ^ ((m >> 2) & 3))) * 8;      // swizzled wf position

    stage(0, 0);
    for (int cb = 0; cb < CB; ++cb) {
        __syncthreads();                     // buf(cb) ready (vmcnt drain)
        if (cb + 1 < CB) stage((cb + 1) & 1, cb + 1);    // overlaps compute(cb)
        const short* sb = sIn + (cb & 1) * BUF;
        const short* sw = sb + SLAB;

        #pragma unroll
        for (int dxr = 0; dxr < 3; ++dxr) {
            int xx = m + dxr;                             // slab col (nt=0)
            const short* colp = sb + xx * 32 + (g ^ ((xx >> 2) & 3)) * 8;
            bf16x8 Bf[4][2];
            #pragma unroll
            for (int rr = 0; rr < 4; ++rr) {              // slab rows 2w..2w+3
                const short* rp = colp + (wave * 2 + rr) * (34 * 32);
                Bf[rr][0] = *(const bf16x8*)rp;
                Bf[rr][1] = *(const bf16x8*)(rp + 16 * 32);   // +16 x (same swz)
            }
            #pragma unroll
            for (int dyi = 0; dyi < 3; ++dyi) {
                int s = dyi * 3 + dxr;
                bf16x8 wf0 = *(const bf16x8*)(sw + s * 1024 + wfoff);
                bf16x8 wf1 = *(const bf16x8*)(sw + s * 1024 + 512 + wfoff);
                #pragma unroll
                for (int wy = 0; wy < 2; ++wy) {
                    int rr = wy + dyi;
                    acc[wy][0][0] = __builtin_amdgcn_mfma_f32_16x16x32_bf16(wf0, Bf[rr][0], acc[wy][0][0], 0, 0, 0);
                    acc[wy][1][0] = __builtin_amdgcn_mfma_f32_16x16x32_bf16(wf1, Bf[rr][0], acc[wy][1][0], 0, 0, 0);
                    acc[wy][0][1] = __builtin_amdgcn_mfma_f32_16x16x32_bf16(wf0, Bf[rr][1], acc[wy][0][1], 0, 0, 0);
                    acc[wy][1][1] = __builtin_amdgcn_mfma_f32_16x16x32_bf16(wf1, Bf[rr][1], acc[wy][1][1], 0, 0, 0);
                }
            }
        }
    }

    // D layout: row (= co-in-tile) = g*4 + reg, col (= x-offset) = lane&15.
    if (FUSE) {
        float wv[2][4];
        #pragma unroll
        for (int mt = 0; mt < 2; ++mt)
            #pragma unroll
            for (int r = 0; r < 4; ++r) wv[mt][r] = wo[mt * 16 + g * 4 + r];
        #pragma unroll
        for (int wy = 0; wy < 2; ++wy) {
            int y = y0 + wave * 2 + wy;
            #pragma unroll
            for (int nt = 0; nt < 2; ++nt) {
                float s = 0.f;
                #pragma unroll
                for (int mt = 0; mt < 2; ++mt)
                    #pragma unroll
                    for (int r = 0; r < 4; ++r)
                        s = fmaf(fmaxf(acc[wy][mt][nt][r], 0.f), wv[mt][r], s);
                s += __shfl_xor(s, 16);
                s += __shfl_xor(s, 32);
                if (g == 0)
                    outF[(size_t)(b * 256 + y) * 256 + x0 + nt * 16 + m]
                        = 1.f / (1.f + expf(-s));
            }
        }
    } else {
        short* outS = (short*)outA;
        #pragma unroll
        for (int wy = 0; wy < 2; ++wy) {
            int y = y0 + wave * 2 + wy;
            #pragma unroll
            for (int nt = 0; nt < 2; ++nt) {
                int x = x0 + nt * 16 + m;
                size_t base = ((size_t)((b * 256 + y) * 256 + x)) * 32;
                #pragma unroll
                for (int mt = 0; mt < 2; ++mt) {
                    int co = mt * 16 + g * 4;
                    s16x4 ov;
                    #pragma unroll
                    for (int r = 0; r < 4; ++r) {
                        float v = acc[wy][mt][nt][r];
                        if (RELU) v = fmaxf(v, 0.f);
                        ov[r] = bf16bits(v);
                    }
                    *(s16x4*)(outS + base + co) = ov;
                }
            }
        }
    }
}

// ---------------------------------------------------------------------------
// Segmented IRNN, both directions fused per dispatch via LDS row-cache
// (|w|<=0.2: 16-step warm-up => segment-parallel scan exact to ~1e-11).
// Writes PLANAR padded dir planes -> fully dense full-line stores.
// VERT: block = 8 x-cols x 32 c, seg of 32 rows; stage rows [y1-16, y1+48)
// once (32 KiB), scan down (plane 2) and up (plane 0) from LDS.
// ---------------------------------------------------------------------------
__global__ __launch_bounds__(256) void irnn_vert(const __hip_bfloat16* __restrict__ A,
        const float* __restrict__ w4, const float* __restrict__ b4,
        __hip_bfloat16* __restrict__ I)
{
    __shared__ short sA[64 * 256];            // [slot 64][xo 8 * c 32]
    int tid = threadIdx.x;
    int c = tid & 31, xo = tid >> 5;
    int x = blockIdx.x * 8 + xo;
    int y1 = blockIdx.y * 32;
    int b = blockIdx.z;
    const short* aS = (const short*)A;

    for (int i = tid; i < 2048; i += 256) {   // 16 B chunks
        int slot = i >> 5, c8 = i & 31;
        int y = y1 - 16 + slot;
        if ((unsigned)y < (unsigned)Hn) {
            const short* gp = aS + ((size_t)(b * 256 + y) * 256 + blockIdx.x * 8) * 32 + c8 * 8;
            *(i32x4*)(sA + slot * 256 + c8 * 8) = *(const i32x4*)gp;
        }
    }
    __syncthreads();

    float wd = w4[64 + c], bd = b4[64 + c];
    float wu = w4[c],      bu = b4[c];
    short* od = (short*)I + ((size_t)(2 * 8 + b) * PB + (size_t)HP + 1 + x) * 32 + c;
    short* ou = (short*)I + ((size_t)(0 * 8 + b) * PB + (size_t)HP + 1 + x) * 32 + c;
    const size_t os = (size_t)HP * 32;

    // down (dir 2): forward
    {
        int ys = y1 ? y1 - 16 : 0;
        float h = bits2f(sA[(ys - y1 + 16) * 256 + tid]);
        if (ys == y1) od[(size_t)y1 * os] = bf16bits(h);
        #pragma unroll 8
        for (int y = ys + 1; y < y1 + 32; ++y) {
            float xv = bits2f(sA[(y - y1 + 16) * 256 + tid]);
            h = fmaxf(fmaf(wd, h, bd + xv), 0.f);
            if (y >= y1) od[(size_t)y * os] = bf16bits(h);
        }
    }
    // up (dir 0): backward
    {
        int ye = (y1 + 47 > 255) ? 255 : y1 + 47;
        float h = bits2f(sA[(ye - y1 + 16) * 256 + tid]);
        if (ye == y1 + 31) ou[(size_t)ye * os] = bf16bits(h);
        #pragma unroll 8
        for (int y = ye - 1; y >= y1; --y) {
            float xv = bits2f(sA[(y - y1 + 16) * 256 + tid]);
            h = fmaxf(fmaf(wu, h, bu + xv), 0.f);
            if (y <= y1 + 31) ou[(size_t)y * os] = bf16bits(h);
        }
    }
}

// HORIZ: block = 8 y-rows x 32 c, seg of 32 cols; stage cols [x1-16, x1+48).
// right -> plane 1, left -> plane 3.
__global__ __launch_bounds__(256) void irnn_horiz(const __hip_bfloat16* __restrict__ A,
        const float* __restrict__ w4, const float* __restrict__ b4,
        __hip_bfloat16* __restrict__ I)
{
    __shared__ short sA[8 * 64 * 32];         // [yo 8][slot 64][c 32]
    int tid = threadIdx.x;
    int c = tid & 31, yo = tid >> 5;
    int y = blockIdx.x * 8 + yo;
    int x1 = blockIdx.y * 32;
    int b = blockIdx.z;
    const short* aS = (const short*)A;

    for (int i = tid; i < 2048; i += 256) {   // 16 B chunks
        int yy = i >> 8, rem = i & 255;       // rem = slot*4 + c16
        int slot = rem >> 2, c16 = rem & 3;
        int x = x1 - 16 + slot;
        if ((unsigned)x < (unsigned)Wn) {
            const short* gp = aS + ((size_t)(b * 256 + blockIdx.x * 8 + yy) * 256 + x) * 32 + c16 * 8;
            *(i32x4*)(sA + (yy * 64 + slot) * 32 + c16 * 8) = *(const i32x4*)gp;
        }
    }
    __syncthreads();

    float wr = w4[32 + c], br = b4[32 + c];
    float wl = w4[96 + c], bl = b4[96 + c];
    short* orr = (short*)I + ((size_t)(1 * 8 + b) * PB + (size_t)(1 + y) * HP + 1) * 32 + c;
    short* ol  = (short*)I + ((size_t)(3 * 8 + b) * PB + (size_t)(1 + y) * HP + 1) * 32 + c;
    const short* sRow = sA + yo * 64 * 32 + c;

    // right (dir 1): forward
    {
        int xs = x1 ? x1 - 16 : 0;
        float h = bits2f(sRow[(xs - x1 + 16) * 32]);
        if (xs == x1) orr[(size_t)x1 * 32] = bf16bits(h);
        #pragma unroll 8
        for (int x = xs + 1; x < x1 + 32; ++x) {
            float xv = bits2f(sRow[(x - x1 + 16) * 32]);
            h = fmaxf(fmaf(wr, h, br + xv), 0.f);
            if (x >= x1) orr[(size_t)x * 32] = bf16bits(h);
        }
    }
    // left (dir 3): backward
    {
        int xe = (x1 + 47 > 255) ? 255 : x1 + 47;
        float h = bits2f(sRow[(xe - x1 + 16) * 32]);
        if (xe == x1 + 31) ol[(size_t)xe * 32] = bf16bits(h);
        #pragma unroll 8
        for (int x = xe - 1; x >= x1; --x) {
            float xv = bits2f(sRow[(x - x1 + 16) * 32]);
            h = fmaxf(fmaf(wl, h, bl + xv), 0.f);
            if (x <= x1 + 31) ol[(size_t)x * 32] = bf16bits(h);
        }
    }
}

// ---------------------------------------------------------------------------
extern "C" void kernel_launch(void* const* d_in, const int* in_sizes, int n_in,
                              void* d_out, int out_size, void* d_ws, size_t ws_size,
                              hipStream_t stream)
{
    const float* x    = (const float*)d_in[0];
    const float* w_in = (const float*)d_in[1];
    const float* w2   = (const float*)d_in[2];
    const float* w3   = (const float*)d_in[3];
    const float* wo   = (const float*)d_in[4];
    const float* i1w  = (const float*)d_in[5];
    const float* i1b  = (const float*)d_in[6];
    const float* i2w  = (const float*)d_in[7];
    const float* i2b  = (const float*)d_in[8];
    float* out = (float*)d_out;

    char* ws = (char*)d_ws;
    // Ipad: PLANAR padded bf16 [dir:4][b:8][258][258][32] = 130 MiB @ 0
    //   (xTpad [8][258][258][32] aliases plane 0; dead before irnn1 writes it)
    __hip_bfloat16* Ipad  = (__hip_bfloat16*)ws;
    __hip_bfloat16* xTpad = (__hip_bfloat16*)ws;
    // A: NHWC bf16 [8][256][256][32] = 32 MiB @ 137 MB
    __hip_bfloat16* A = (__hip_bfloat16*)(ws + ((size_t)137 << 20));
    // packed weights @ 170 MiB
    __hip_bfloat16* wp1 = (__hip_bfloat16*)(ws + ((size_t)170 << 20));
    __hip_bfloat16* wp2 = (__hip_bfloat16*)(ws + ((size_t)170 << 20) + ((size_t)1 << 19));
    __hip_bfloat16* wp3 = (__hip_bfloat16*)(ws + ((size_t)170 << 20) + ((size_t)2 << 19));

    dim3 convGrid(8, 32, 8);      // 32-x strips, 8-y chunks, 8 b = 2048 blocks
    dim3 irnnGrid(32, 8, 8);      // 8-line chunks, 8 segs(32), 8 b = 2048 blocks

    pack_w<32> <<<36,  256, 0, stream>>>(w_in, wp1);
    pack_w<128><<<144, 256, 0, stream>>>(w2, wp2);
    pack_w<128><<<144, 256, 0, stream>>>(w3, wp3);

    // zero borders of all 32 padded planes (covers xTpad = plane 0 too)
    zero_border<32><<<514, 256, 0, stream>>>((short*)Ipad);
    x_to_nhwc<<<dim3(2048, 8), 256, 0, stream>>>(x, xTpad);
    conv_mfma<32, false, false><<<convGrid, 256, 0, stream>>>(xTpad, wp1, A, nullptr, nullptr);

    irnn_vert <<<irnnGrid, 256, 0, stream>>>(A, i1w, i1b, Ipad);
    irnn_horiz<<<irnnGrid, 256, 0, stream>>>(A, i1w, i1b, Ipad);
    conv_mfma<128, false, false><<<convGrid, 256, 0, stream>>>(Ipad, wp2, A, nullptr, nullptr);

    irnn_vert <<<irnnGrid, 256, 0, stream>>>(A, i2w, i2b, Ipad);
    irnn_horiz<<<irnnGrid, 256, 0, stream>>>(A, i2w, i2b, Ipad);
    // conv3 + relu + conv1x1 + sigmoid fused; writes fp32 mask directly
    conv_mfma<128, true, true><<<convGrid, 256, 0, stream>>>(Ipad, wp3, nullptr, wo, out);
}